// Round 1
// baseline (507.616 us; speedup 1.0000x reference)
//
#include <hip/hip_runtime.h>
#include <math.h>

// Correlation layer: out[b,d,h,w] = (1/sqrt(C)) * sum_c x1[b,c,h,w] * x2[b,c,h+i,w+j]
// d enumerates (i,j) in [-4,4]^2 row-major, excluding (0,0). Zero-padded x2.
// Shapes fixed by the reference: B=8, C=128, H=128, W=192 -> out (8,80,128,192) fp32.

#define B_  8
#define C_  128
#define H_  128
#define W_  192
#define HALO 4
#define TH 8
#define TW 32
#define XH (TH + 2*HALO)   // 16
#define XW (TW + 2*HALO)   // 40
#define CC 4               // channels staged per chunk

__global__ __launch_bounds__(256, 4) void corr_kernel(
    const float* __restrict__ x1, const float* __restrict__ x2,
    float* __restrict__ out)
{
    __shared__ float s2[CC][XH][XW];   // 4*16*40*4 = 10240 B

    const int tx = threadIdx.x;              // 0..31
    const int ty = threadIdx.y;              // 0..7
    const int tid = ty * TW + tx;            // 0..255

    const int bw = blockIdx.x;               // 0..5
    const int bh = blockIdx.y;               // 0..15
    const int b  = blockIdx.z;               // 0..7

    const int w0 = bw * TW, h0 = bh * TH;
    const int h = h0 + ty, w = w0 + tx;

    float acc[81];
    #pragma unroll
    for (int k = 0; k < 81; k++) acc[k] = 0.f;

    const int HW = H_ * W_;
    const float* x1p = x1 + (size_t)b * C_ * HW + h * W_ + w;
    const float* x2b = x2 + (size_t)b * C_ * HW;

    for (int c0 = 0; c0 < C_; c0 += CC) {
        __syncthreads();   // previous chunk's reads done before overwrite
        // Stage CC channels of the x2 halo tile (zero-fill out of bounds).
        #pragma unroll
        for (int e = tid; e < CC * XH * XW; e += 256) {
            const int cc  = e / (XH * XW);
            const int rem = e - cc * (XH * XW);
            const int r   = rem / XW;
            const int col = rem - r * XW;
            const int gh = h0 - HALO + r;
            const int gw = w0 - HALO + col;
            float v = 0.f;
            if ((unsigned)gh < (unsigned)H_ && (unsigned)gw < (unsigned)W_)
                v = x2b[(size_t)(c0 + cc) * HW + gh * W_ + gw];
            s2[cc][r][col] = v;
        }
        __syncthreads();

        #pragma unroll
        for (int cc = 0; cc < CC; cc++) {
            const float a = x1p[(size_t)(c0 + cc) * HW];
            #pragma unroll
            for (int i = 0; i < 9; i++) {
                const float* row = &s2[cc][ty + i][tx];
                #pragma unroll
                for (int j = 0; j < 9; j++) {
                    acc[i * 9 + j] = fmaf(a, row[j], acc[i * 9 + j]);
                }
            }
        }
    }

    const float scale = 1.0f / sqrtf((float)C_);
    const size_t outBase = (size_t)b * 80 * HW + (size_t)h * W_ + w;
    int d = 0;
    #pragma unroll
    for (int t = 0; t < 81; t++) {
        if (t == 40) continue;        // skip (i,j)=(0,0)
        out[outBase + (size_t)d * HW] = acc[t] * scale;
        d++;
    }
}

extern "C" void kernel_launch(void* const* d_in, const int* in_sizes, int n_in,
                              void* d_out, int out_size, void* d_ws, size_t ws_size,
                              hipStream_t stream) {
    const float* x1 = (const float*)d_in[0];
    const float* x2 = (const float*)d_in[1];
    float* out = (float*)d_out;

    dim3 block(TW, TH);                      // 32 x 8 = 256
    dim3 grid(W_ / TW, H_ / TH, B_);         // 6 x 16 x 8 = 768 blocks
    corr_kernel<<<grid, block, 0, stream>>>(x1, x2, out);
}